// Round 1
// baseline (330.461 us; speedup 1.0000x reference)
//
#include <hip/hip_runtime.h>
#include <math.h>

#define NB 4
#define NN 10000
#define NC 128
#define NH 128
#define NE 160000
#define DIN 256   // C+H
#define DOUT 512  // 4H
#define MT 16     // GEMM row tile

// ---------------- graph prep ----------------

__global__ void k_init(float* deg, int* cnt, int* cursor) {
    int i = blockIdx.x * blockDim.x + threadIdx.x;
    if (i < NN) { deg[i] = 1.0f; cnt[i] = 0; cursor[i] = 0; }  // self-loop weight 1.0 pre-added
}

__global__ void k_pack(const float* __restrict__ Wi, const float* __restrict__ Wf,
                       const float* __restrict__ Wo, const float* __restrict__ Wg,
                       const float* __restrict__ bi, const float* __restrict__ bf,
                       const float* __restrict__ bo, const float* __restrict__ bg,
                       float* __restrict__ Wcat, float* __restrict__ bcat) {
    int i = blockIdx.x * blockDim.x + threadIdx.x;
    if (i < DIN * DOUT) {
        int k = i >> 9;          // /512
        int cidx = i & 511;
        int g = cidx >> 7, j = cidx & 127;
        const float* W = (g == 0) ? Wi : (g == 1) ? Wf : (g == 2) ? Wo : Wg;
        Wcat[i] = W[k * NH + j];
    }
    if (i < DOUT) {
        int g = i >> 7, j = i & 127;
        const float* bb = (g == 0) ? bi : (g == 1) ? bf : (g == 2) ? bo : bg;
        bcat[i] = bb[j];
    }
}

__global__ void k_degcnt(const int* __restrict__ ei, const float* __restrict__ ew,
                         float* deg, int* cnt) {
    int e = blockIdx.x * blockDim.x + threadIdx.x;
    if (e < NE) {
        int dst = ei[NE + e];
        atomicAdd(&deg[dst], ew[e]);
        atomicAdd(&cnt[dst], 1);
    }
}

__global__ void k_rsqrt(float* deg) {  // in-place deg -> dinv
    int i = blockIdx.x * blockDim.x + threadIdx.x;
    if (i < NN) { float d = deg[i]; deg[i] = (d > 0.f) ? rsqrtf(d) : 0.f; }
}

// single-block exclusive scan of cnt -> offsets (N=10000, chunks of 1024)
__global__ void k_scan(const int* __restrict__ cnt, int* __restrict__ offsets) {
    __shared__ int lds[1024];
    __shared__ int carry;
    int t = threadIdx.x;
    if (t == 0) { carry = 0; offsets[0] = 0; }
    __syncthreads();
    for (int base = 0; base < NN; base += 1024) {
        int v = (base + t < NN) ? cnt[base + t] : 0;
        lds[t] = v;
        __syncthreads();
        for (int off = 1; off < 1024; off <<= 1) {
            int add = (t >= off) ? lds[t - off] : 0;
            __syncthreads();
            lds[t] += add;
            __syncthreads();
        }
        if (base + t < NN) offsets[base + t + 1] = carry + lds[t];
        __syncthreads();
        if (t == 0) carry += lds[1023];
        __syncthreads();
    }
}

__global__ void k_fill(const int* __restrict__ ei, const float* __restrict__ ew,
                       const float* __restrict__ dinv, const int* __restrict__ offsets,
                       int* cursor, int2* __restrict__ ebuf) {
    int e = blockIdx.x * blockDim.x + threadIdx.x;
    if (e < NE) {
        int src = ei[e], dst = ei[NE + e];
        float norm = dinv[src] * ew[e] * dinv[dst];
        int pos = offsets[dst] + atomicAdd(&cursor[dst], 1);
        ebuf[pos] = make_int2(src, __float_as_int(norm));
    }
}

// ---------------- aggregation: one block per dst node ----------------
// agg[(b*NN+n)*256 + k] = sum_{e: dst=n} norm_e * xh[b, src_e, k]  + dinv[n]^2 * xh[b,n,k]
__global__ __launch_bounds__(256) void k_agg(const float* __restrict__ x,
                                             const float* __restrict__ h,
                                             const float* __restrict__ dinv,
                                             const int* __restrict__ offsets,
                                             const int2* __restrict__ ebuf,
                                             float* __restrict__ agg) {
    int n = blockIdx.x;
    int k = threadIdx.x;  // 0..255
    const float* base = (k < NC) ? (x + k) : (h + (k - NC));
    const long bs = (long)NN * 128;  // batch stride (same for x and h since C==H==128)

    float acc0 = 0.f, acc1 = 0.f, acc2 = 0.f, acc3 = 0.f;
    int beg = offsets[n], end = offsets[n + 1];
    for (int j = beg; j < end; ++j) {
        int2 e = ebuf[j];
        const float* p = base + (long)e.x * 128;
        float w = __int_as_float(e.y);
        acc0 = fmaf(w, p[0], acc0);
        acc1 = fmaf(w, p[bs], acc1);
        acc2 = fmaf(w, p[2 * bs], acc2);
        acc3 = fmaf(w, p[3 * bs], acc3);
    }
    // self loop: norm = dinv[n]*1.0*dinv[n]
    float di = dinv[n];
    float wl = di * di;
    const float* ps = base + (long)n * 128;
    acc0 = fmaf(wl, ps[0], acc0);
    acc1 = fmaf(wl, ps[bs], acc1);
    acc2 = fmaf(wl, ps[2 * bs], acc2);
    acc3 = fmaf(wl, ps[3 * bs], acc3);

    agg[((long)0 * NN + n) * DIN + k] = acc0;
    agg[((long)1 * NN + n) * DIN + k] = acc1;
    agg[((long)2 * NN + n) * DIN + k] = acc2;
    agg[((long)3 * NN + n) * DIN + k] = acc3;
}

// ---------------- fused GEMM (40000x256 @ 256x512) + LSTM gates ----------------
__global__ __launch_bounds__(256) void k_gemm(const float* __restrict__ agg,
                                              const float* __restrict__ Wcat,
                                              const float* __restrict__ bcat,
                                              const float* __restrict__ c_in,
                                              float* __restrict__ out) {
    __shared__ float Bs[16][512];  // K-chunk of W; reused as 16x512 output tile in epilogue
    __shared__ float As[16][16];   // As[k][row]
    int t = threadIdx.x;
    int cg = t & 63, rg = t >> 6;
    int rowbase = blockIdx.x * MT;

    float acc[4][8];
#pragma unroll
    for (int r = 0; r < 4; ++r)
#pragma unroll
        for (int c2 = 0; c2 < 8; ++c2) acc[r][c2] = 0.f;

    for (int kb = 0; kb < DIN; kb += 16) {
        __syncthreads();
        {
            const float4* Wv = (const float4*)(Wcat + (long)kb * DOUT);
            float4* Bv = (float4*)&Bs[0][0];
#pragma unroll
            for (int i = 0; i < 8; ++i) Bv[t + i * 256] = Wv[t + i * 256];
            int r = t >> 4, kk = t & 15;
            As[kk][r] = agg[(long)(rowbase + r) * DIN + kb + kk];
        }
        __syncthreads();
#pragma unroll
        for (int kk = 0; kk < 16; ++kk) {
            float4 a = *(const float4*)&As[kk][rg * 4];
            float4 b0 = *(const float4*)&Bs[kk][cg * 8];
            float4 b1 = *(const float4*)&Bs[kk][cg * 8 + 4];
            float av[4] = {a.x, a.y, a.z, a.w};
            float bv[8] = {b0.x, b0.y, b0.z, b0.w, b1.x, b1.y, b1.z, b1.w};
#pragma unroll
            for (int r = 0; r < 4; ++r)
#pragma unroll
                for (int c2 = 0; c2 < 8; ++c2) acc[r][c2] = fmaf(av[r], bv[c2], acc[r][c2]);
        }
    }
    __syncthreads();
#pragma unroll
    for (int r = 0; r < 4; ++r) {
        *(float4*)&Bs[rg * 4 + r][cg * 8] = make_float4(acc[r][0], acc[r][1], acc[r][2], acc[r][3]);
        *(float4*)&Bs[rg * 4 + r][cg * 8 + 4] = make_float4(acc[r][4], acc[r][5], acc[r][6], acc[r][7]);
    }
    __syncthreads();
#pragma unroll
    for (int p = 0; p < 8; ++p) {
        int idx = p * 256 + t;
        int row = idx >> 7, j = idx & 127;
        float vi = Bs[row][j] + bcat[j];
        float vf = Bs[row][128 + j] + bcat[128 + j];
        float vo = Bs[row][256 + j] + bcat[256 + j];
        float vg = Bs[row][384 + j] + bcat[384 + j];
        float ig = 1.f / (1.f + __expf(-vi));
        float fg = 1.f / (1.f + __expf(-vf));
        float og = 1.f / (1.f + __expf(-vo));
        float gg = tanhf(vg);
        long grow = (long)rowbase + row;
        float co = c_in[grow * 128 + j];
        float cn = fg * co + ig * gg;
        float hn = og * tanhf(cn);
        out[grow * 128 + j] = hn;
        out[(long)NB * NN * 128 + grow * 128 + j] = cn;
    }
}

// ---------------- launch ----------------

extern "C" void kernel_launch(void* const* d_in, const int* in_sizes, int n_in,
                              void* d_out, int out_size, void* d_ws, size_t ws_size,
                              hipStream_t stream) {
    const float* x = (const float*)d_in[0];
    const float* h = (const float*)d_in[1];
    const float* c = (const float*)d_in[2];
    const int* ei = (const int*)d_in[3];
    const float* ew = (const float*)d_in[4];
    const float* Wi = (const float*)d_in[5];
    const float* bi = (const float*)d_in[6];
    const float* Wf = (const float*)d_in[7];
    const float* bf = (const float*)d_in[8];
    const float* Wo = (const float*)d_in[9];
    const float* bo = (const float*)d_in[10];
    const float* Wg = (const float*)d_in[11];
    const float* bg = (const float*)d_in[12];
    float* out = (float*)d_out;

    char* ws = (char*)d_ws;
    size_t off = 0;
    auto alloc = [&](size_t bytes) {
        void* p = ws + off;
        off = (off + bytes + 255) & ~(size_t)255;
        return p;
    };
    float* deg = (float*)alloc((size_t)NN * 4);       // becomes dinv after k_rsqrt
    int* cnt = (int*)alloc((size_t)NN * 4);
    int* offsets = (int*)alloc((size_t)(NN + 1) * 4);
    int* cursor = (int*)alloc((size_t)NN * 4);
    float* bcat = (float*)alloc((size_t)DOUT * 4);
    float* Wcat = (float*)alloc((size_t)DIN * DOUT * 4);
    int2* ebuf = (int2*)alloc((size_t)NE * 8);
    float* agg = (float*)alloc((size_t)NB * NN * DIN * 4);

    hipLaunchKernelGGL(k_init, dim3((NN + 255) / 256), dim3(256), 0, stream, deg, cnt, cursor);
    hipLaunchKernelGGL(k_pack, dim3((DIN * DOUT + 255) / 256), dim3(256), 0, stream,
                       Wi, Wf, Wo, Wg, bi, bf, bo, bg, Wcat, bcat);
    hipLaunchKernelGGL(k_degcnt, dim3((NE + 255) / 256), dim3(256), 0, stream, ei, ew, deg, cnt);
    hipLaunchKernelGGL(k_rsqrt, dim3((NN + 255) / 256), dim3(256), 0, stream, deg);
    hipLaunchKernelGGL(k_scan, dim3(1), dim3(1024), 0, stream, cnt, offsets);
    hipLaunchKernelGGL(k_fill, dim3((NE + 255) / 256), dim3(256), 0, stream, ei, ew, deg, offsets, cursor, ebuf);
    hipLaunchKernelGGL(k_agg, dim3(NN), dim3(256), 0, stream, x, h, deg, offsets, ebuf, agg);
    hipLaunchKernelGGL(k_gemm, dim3(NB * NN / MT), dim3(256), 0, stream, agg, Wcat, bcat, c, out);
}

// Round 2
// 172.354 us; speedup vs baseline: 1.9173x; 1.9173x over previous
//
#include <hip/hip_runtime.h>
#include <math.h>

#define NB 4
#define NN 10000
#define NC 128
#define NH 128
#define NE 160000
#define DIN 256   // C+H
#define DOUT 512  // 4H

typedef short bf16x8 __attribute__((ext_vector_type(8)));
typedef float f32x4 __attribute__((ext_vector_type(4)));

__device__ inline unsigned short f2bf(float f) {
    unsigned int u = __float_as_uint(f);
    unsigned int r = (u + 0x7fffu + ((u >> 16) & 1u)) >> 16;
    return (unsigned short)r;
}
__device__ inline float bf2f(unsigned short u) {
    return __uint_as_float(((unsigned int)u) << 16);
}

// ---------------- graph prep ----------------

__global__ void k_init(float* deg, int* cnt, int* cursor) {
    int i = blockIdx.x * blockDim.x + threadIdx.x;
    if (i < NN) { deg[i] = 1.0f; cnt[i] = 0; cursor[i] = 0; }  // self-loop weight pre-added
}

// Pack W^T bf16 [512][256]: Wt[g*128+j][k] = W_g[k][j]; bcat fp32 gate-major.
__global__ void k_pack(const float* __restrict__ Wi, const float* __restrict__ Wf,
                       const float* __restrict__ Wo, const float* __restrict__ Wg,
                       const float* __restrict__ bi, const float* __restrict__ bf,
                       const float* __restrict__ bo, const float* __restrict__ bg,
                       unsigned short* __restrict__ Wt, float* __restrict__ bcat) {
    int i = blockIdx.x * blockDim.x + threadIdx.x;
    if (i < DOUT * DIN) {
        int n = i >> 8, k = i & 255;
        int g = n >> 7, j = n & 127;
        const float* W = (g == 0) ? Wi : (g == 1) ? Wf : (g == 2) ? Wo : Wg;
        Wt[i] = f2bf(W[k * NH + j]);
    }
    if (i < DOUT) {
        int g = i >> 7, j = i & 127;
        const float* bb = (g == 0) ? bi : (g == 1) ? bf : (g == 2) ? bo : bg;
        bcat[i] = bb[j];
    }
}

__global__ void k_degcnt(const int* __restrict__ ei, const float* __restrict__ ew,
                         float* deg, int* cnt) {
    int e = blockIdx.x * blockDim.x + threadIdx.x;
    if (e < NE) {
        int dst = ei[NE + e];
        atomicAdd(&deg[dst], ew[e]);
        atomicAdd(&cnt[dst], 1);
    }
}

__global__ void k_rsqrt(float* deg) {  // in-place deg -> dinv
    int i = blockIdx.x * blockDim.x + threadIdx.x;
    if (i < NN) { float d = deg[i]; deg[i] = (d > 0.f) ? rsqrtf(d) : 0.f; }
}

// single-block scan: 1024 threads x 10 elems each, wave-shfl scan, 2 barriers
__global__ __launch_bounds__(1024) void k_scan(const int* __restrict__ cnt,
                                               int* __restrict__ offsets) {
    __shared__ int wsum[16];
    int t = threadIdx.x;
    int base = t * 10;
    int loc[10];
    int s = 0;
#pragma unroll
    for (int i = 0; i < 10; ++i) {
        int idx = base + i;
        int v = (idx < NN) ? cnt[idx] : 0;
        loc[i] = s;
        s += v;
    }
    int lane = t & 63, w = t >> 6;
    int inc = s;
    for (int o = 1; o < 64; o <<= 1) {
        int u = __shfl_up(inc, o);
        if (lane >= o) inc += u;
    }
    if (lane == 63) wsum[w] = inc;
    __syncthreads();
    if (t < 16) {
        int v = wsum[t];
        for (int o = 1; o < 16; o <<= 1) {
            int u = __shfl_up(v, o);
            if (t >= o) v += u;
        }
        wsum[t] = v;
    }
    __syncthreads();
    int wave_excl = (w > 0) ? wsum[w - 1] : 0;
    int thread_excl = wave_excl + inc - s;
#pragma unroll
    for (int i = 0; i < 10; ++i) {
        int idx = base + i;
        if (idx < NN) offsets[idx] = thread_excl + loc[i];
    }
    if (t == 0) offsets[NN] = wsum[15];
}

__global__ void k_fill(const int* __restrict__ ei, const float* __restrict__ ew,
                       const float* __restrict__ dinv, const int* __restrict__ offsets,
                       int* cursor, int2* __restrict__ ebuf) {
    int e = blockIdx.x * blockDim.x + threadIdx.x;
    if (e < NE) {
        int src = ei[e], dst = ei[NE + e];
        float norm = dinv[src] * ew[e] * dinv[dst];
        int pos = offsets[dst] + atomicAdd(&cursor[dst], 1);
        ebuf[pos] = make_int2(src, __float_as_int(norm));
    }
}

// convert x||h -> bf16 xhb[4][10000][256]; each thread handles 8 floats
__global__ __launch_bounds__(256) void k_cvt(const float* __restrict__ x,
                                             const float* __restrict__ h,
                                             unsigned short* __restrict__ xhb) {
    int id = blockIdx.x * 256 + threadIdx.x;  // 0 .. 1,279,999
    int f8 = id * 8;
    int col = f8 & 255;
    int row = f8 >> 8;   // b*NN+n
    int half = col >> 7;
    int c7 = col & 127;
    const float* src = (half ? h : x) + (size_t)row * 128 + c7;
    float4 v0 = *(const float4*)src;
    float4 v1 = *(const float4*)(src + 4);
    bf16x8 o;
    o[0] = (short)f2bf(v0.x); o[1] = (short)f2bf(v0.y);
    o[2] = (short)f2bf(v0.z); o[3] = (short)f2bf(v0.w);
    o[4] = (short)f2bf(v1.x); o[5] = (short)f2bf(v1.y);
    o[6] = (short)f2bf(v1.z); o[7] = (short)f2bf(v1.w);
    *(bf16x8*)(xhb + (size_t)f8) = o;
}

// ---------------- aggregation: one block per dst node ----------------
// lane-batch layout: thread t -> batch b = t>>6, feature quad k4 = (t&63)*4
__global__ __launch_bounds__(256) void k_agg(const unsigned short* __restrict__ xhb,
                                             const float* __restrict__ dinv,
                                             const int* __restrict__ offsets,
                                             const int2* __restrict__ ebuf,
                                             unsigned short* __restrict__ aggb) {
    int n = blockIdx.x;
    int t = threadIdx.x;
    int b = t >> 6;
    int k4 = (t & 63) * 4;
    const unsigned short* base = xhb + (size_t)b * NN * 256 + k4;

    float a0 = 0.f, a1 = 0.f, a2 = 0.f, a3 = 0.f;
    int beg = offsets[n], end = offsets[n + 1];
    for (int j = beg; j < end; ++j) {
        int2 e = ebuf[j];
        float w = __int_as_float(e.y);
        ushort4 v = *(const ushort4*)(base + (size_t)e.x * 256);
        a0 = fmaf(w, bf2f(v.x), a0);
        a1 = fmaf(w, bf2f(v.y), a1);
        a2 = fmaf(w, bf2f(v.z), a2);
        a3 = fmaf(w, bf2f(v.w), a3);
    }
    float di = dinv[n];
    float wl = di * di;
    ushort4 vs = *(const ushort4*)(base + (size_t)n * 256);
    a0 = fmaf(wl, bf2f(vs.x), a0);
    a1 = fmaf(wl, bf2f(vs.y), a1);
    a2 = fmaf(wl, bf2f(vs.z), a2);
    a3 = fmaf(wl, bf2f(vs.w), a3);

    ushort4 o;
    o.x = f2bf(a0); o.y = f2bf(a1); o.z = f2bf(a2); o.w = f2bf(a3);
    *(ushort4*)(aggb + ((size_t)b * NN + n) * 256 + k4) = o;
}

// ---------------- MFMA GEMM (40000x256 @ 256^T x 512) + fused LSTM gates ----------------
// block: 64 rows x 32 j-cols; 4 waves (wm 0..1, wn 0..1); wave: 32 rows x 16 j x 4 gates
__global__ __launch_bounds__(256) void k_gemm(const unsigned short* __restrict__ aggb,
                                              const unsigned short* __restrict__ Wt,
                                              const float* __restrict__ bcat,
                                              const float* __restrict__ c_in,
                                              float* __restrict__ out) {
    int t = threadIdx.x;
    int lane = t & 63, wid = t >> 6;
    int wm = wid >> 1, wn = wid & 1;
    int bid = blockIdx.x;          // 0..2499
    int bm = bid >> 2, bn = bid & 3;
    int rowbase = bm * 64 + wm * 32;
    int jbase = bn * 32 + wn * 16;

    int lr = lane & 15;   // A-row / B-col / C-col index
    int lk = lane >> 4;   // k-group

    f32x4 acc[2][4];
#pragma unroll
    for (int mi = 0; mi < 2; ++mi)
#pragma unroll
        for (int g = 0; g < 4; ++g) acc[mi][g] = (f32x4)0.f;

    const unsigned short* A0 = aggb + (size_t)(rowbase + lr) * 256 + lk * 8;
    const unsigned short* A1 = A0 + 16 * 256;
    const unsigned short* B0 = Wt + (size_t)(0 * 128 + jbase + lr) * 256 + lk * 8;
    const unsigned short* B1 = Wt + (size_t)(1 * 128 + jbase + lr) * 256 + lk * 8;
    const unsigned short* B2 = Wt + (size_t)(2 * 128 + jbase + lr) * 256 + lk * 8;
    const unsigned short* B3 = Wt + (size_t)(3 * 128 + jbase + lr) * 256 + lk * 8;

#pragma unroll
    for (int kb = 0; kb < 256; kb += 32) {
        bf16x8 a0 = *(const bf16x8*)(A0 + kb);
        bf16x8 a1 = *(const bf16x8*)(A1 + kb);
        bf16x8 b0 = *(const bf16x8*)(B0 + kb);
        bf16x8 b1 = *(const bf16x8*)(B1 + kb);
        bf16x8 b2 = *(const bf16x8*)(B2 + kb);
        bf16x8 b3 = *(const bf16x8*)(B3 + kb);
        acc[0][0] = __builtin_amdgcn_mfma_f32_16x16x32_bf16(a0, b0, acc[0][0], 0, 0, 0);
        acc[0][1] = __builtin_amdgcn_mfma_f32_16x16x32_bf16(a0, b1, acc[0][1], 0, 0, 0);
        acc[0][2] = __builtin_amdgcn_mfma_f32_16x16x32_bf16(a0, b2, acc[0][2], 0, 0, 0);
        acc[0][3] = __builtin_amdgcn_mfma_f32_16x16x32_bf16(a0, b3, acc[0][3], 0, 0, 0);
        acc[1][0] = __builtin_amdgcn_mfma_f32_16x16x32_bf16(a1, b0, acc[1][0], 0, 0, 0);
        acc[1][1] = __builtin_amdgcn_mfma_f32_16x16x32_bf16(a1, b1, acc[1][1], 0, 0, 0);
        acc[1][2] = __builtin_amdgcn_mfma_f32_16x16x32_bf16(a1, b2, acc[1][2], 0, 0, 0);
        acc[1][3] = __builtin_amdgcn_mfma_f32_16x16x32_bf16(a1, b3, acc[1][3], 0, 0, 0);
    }

    // epilogue: lane holds all 4 gates for (row, j) in acc[mi][g][r]
    int j = jbase + lr;
    float b_i = bcat[j], b_f = bcat[128 + j], b_o = bcat[256 + j], b_g = bcat[384 + j];
#pragma unroll
    for (int mi = 0; mi < 2; ++mi) {
#pragma unroll
        for (int r = 0; r < 4; ++r) {
            int row = rowbase + mi * 16 + lk * 4 + r;
            float vi = acc[mi][0][r] + b_i;
            float vf = acc[mi][1][r] + b_f;
            float vo = acc[mi][2][r] + b_o;
            float vg = acc[mi][3][r] + b_g;
            float ig = 1.f / (1.f + __expf(-vi));
            float fg = 1.f / (1.f + __expf(-vf));
            float og = 1.f / (1.f + __expf(-vo));
            float gg = 1.f - 2.f / (__expf(2.f * vg) + 1.f);
            size_t o = (size_t)row * 128 + j;
            float co = c_in[o];
            float cn = fg * co + ig * gg;
            float tc = 1.f - 2.f / (__expf(2.f * cn) + 1.f);
            float hn = og * tc;
            out[o] = hn;
            out[(size_t)NB * NN * 128 + o] = cn;
        }
    }
}

// ---------------- launch ----------------

extern "C" void kernel_launch(void* const* d_in, const int* in_sizes, int n_in,
                              void* d_out, int out_size, void* d_ws, size_t ws_size,
                              hipStream_t stream) {
    const float* x = (const float*)d_in[0];
    const float* h = (const float*)d_in[1];
    const float* c = (const float*)d_in[2];
    const int* ei = (const int*)d_in[3];
    const float* ew = (const float*)d_in[4];
    const float* Wi = (const float*)d_in[5];
    const float* bi = (const float*)d_in[6];
    const float* Wf = (const float*)d_in[7];
    const float* bf = (const float*)d_in[8];
    const float* Wo = (const float*)d_in[9];
    const float* bo = (const float*)d_in[10];
    const float* Wg = (const float*)d_in[11];
    const float* bg = (const float*)d_in[12];
    float* out = (float*)d_out;

    char* ws = (char*)d_ws;
    size_t off = 0;
    auto alloc = [&](size_t bytes) {
        void* p = ws + off;
        off = (off + bytes + 255) & ~(size_t)255;
        return p;
    };
    float* deg = (float*)alloc((size_t)NN * 4);       // becomes dinv
    int* cnt = (int*)alloc((size_t)NN * 4);
    int* offsets = (int*)alloc((size_t)(NN + 1) * 4);
    int* cursor = (int*)alloc((size_t)NN * 4);
    float* bcat = (float*)alloc((size_t)DOUT * 4);
    unsigned short* Wt = (unsigned short*)alloc((size_t)DOUT * DIN * 2);
    int2* ebuf = (int2*)alloc((size_t)NE * 8);
    unsigned short* xhb = (unsigned short*)alloc((size_t)NB * NN * DIN * 2);
    unsigned short* aggb = (unsigned short*)alloc((size_t)NB * NN * DIN * 2);

    hipLaunchKernelGGL(k_init, dim3((NN + 255) / 256), dim3(256), 0, stream, deg, cnt, cursor);
    hipLaunchKernelGGL(k_pack, dim3((DOUT * DIN + 255) / 256), dim3(256), 0, stream,
                       Wi, Wf, Wo, Wg, bi, bf, bo, bg, Wt, bcat);
    hipLaunchKernelGGL(k_degcnt, dim3((NE + 255) / 256), dim3(256), 0, stream, ei, ew, deg, cnt);
    hipLaunchKernelGGL(k_rsqrt, dim3((NN + 255) / 256), dim3(256), 0, stream, deg);
    hipLaunchKernelGGL(k_scan, dim3(1), dim3(1024), 0, stream, cnt, offsets);
    hipLaunchKernelGGL(k_fill, dim3((NE + 255) / 256), dim3(256), 0, stream, ei, ew, deg, offsets, cursor, ebuf);
    hipLaunchKernelGGL(k_cvt, dim3(NB * NN * DIN / 8 / 256), dim3(256), 0, stream, x, h, xhb);
    hipLaunchKernelGGL(k_agg, dim3(NN), dim3(256), 0, stream, xhb, deg, offsets, ebuf, aggb);
    hipLaunchKernelGGL(k_gemm, dim3(NB * NN / 64 * 4), dim3(256), 0, stream, aggb, Wt, bcat, c, out);
}

// Round 3
// 144.260 us; speedup vs baseline: 2.2907x; 1.1947x over previous
//
#include <hip/hip_runtime.h>
#include <math.h>

#define NB 4
#define NN 10000
#define NE 160000
#define DIN 256   // C+H
#define DOUT 512  // 4H

typedef short bf16x8 __attribute__((ext_vector_type(8)));
typedef float f32x4 __attribute__((ext_vector_type(4)));

#define GLOAD_LDS16(g, l) \
    __builtin_amdgcn_global_load_lds((const __attribute__((address_space(1))) void*)(g), \
                                     (__attribute__((address_space(3))) void*)(l), 16, 0, 0)

__device__ inline unsigned short f2bf(float f) {
    unsigned int u = __float_as_uint(f);
    unsigned int r = (u + 0x7fffu + ((u >> 16) & 1u)) >> 16;
    return (unsigned short)r;
}
__device__ inline float bf2f(unsigned short u) {
    return __uint_as_float(((unsigned int)u) << 16);
}

// ---------------- prep: init + pack W^T bf16 [512][256] ----------------
__global__ void k_pack(const float* __restrict__ Wi, const float* __restrict__ Wf,
                       const float* __restrict__ Wo, const float* __restrict__ Wg,
                       const float* __restrict__ bi, const float* __restrict__ bf,
                       const float* __restrict__ bo, const float* __restrict__ bg,
                       float* __restrict__ deg, int* __restrict__ cnt, int* __restrict__ cursor,
                       unsigned short* __restrict__ Wt, float* __restrict__ bcat) {
    int i = blockIdx.x * 256 + threadIdx.x;
    if (i < NN) { deg[i] = 1.0f; cnt[i] = 0; cursor[i] = 0; }  // self-loop weight pre-added
    if (i < DOUT * DIN) {
        int n = i >> 8, k = i & 255;
        int g = n >> 7, j = n & 127;
        const float* W = (g == 0) ? Wi : (g == 1) ? Wf : (g == 2) ? Wo : Wg;
        Wt[i] = f2bf(W[k * 128 + j]);
    }
    if (i < DOUT) {
        int g = i >> 7, j = i & 127;
        const float* bb = (g == 0) ? bi : (g == 1) ? bf : (g == 2) ? bo : bg;
        bcat[i] = bb[j];
    }
}

__global__ void k_degcnt(const int* __restrict__ ei, const float* __restrict__ ew,
                         float* deg, int* cnt) {
    int e = blockIdx.x * 256 + threadIdx.x;
    if (e < NE) {
        int dst = ei[NE + e];
        atomicAdd(&deg[dst], ew[e]);
        atomicAdd(&cnt[dst], 1);
    }
}

// rsqrt(deg) in-place, then single-block scan of cnt -> offsets
__global__ __launch_bounds__(1024) void k_scanrs(float* __restrict__ deg,
                                                 const int* __restrict__ cnt,
                                                 int* __restrict__ offsets) {
    int t = threadIdx.x;
    for (int i = t; i < NN; i += 1024) {
        float d = deg[i];
        deg[i] = (d > 0.f) ? rsqrtf(d) : 0.f;
    }
    __shared__ int wsum[16];
    int base = t * 10;
    int loc[10];
    int s = 0;
#pragma unroll
    for (int i = 0; i < 10; ++i) {
        int idx = base + i;
        int v = (idx < NN) ? cnt[idx] : 0;
        loc[i] = s;
        s += v;
    }
    int lane = t & 63, w = t >> 6;
    int inc = s;
    for (int o = 1; o < 64; o <<= 1) {
        int u = __shfl_up(inc, o);
        if (lane >= o) inc += u;
    }
    if (lane == 63) wsum[w] = inc;
    __syncthreads();
    if (t < 16) {
        int v = wsum[t];
        for (int o = 1; o < 16; o <<= 1) {
            int u = __shfl_up(v, o);
            if (t >= o) v += u;
        }
        wsum[t] = v;
    }
    __syncthreads();
    int wave_excl = (w > 0) ? wsum[w - 1] : 0;
    int thread_excl = wave_excl + inc - s;
#pragma unroll
    for (int i = 0; i < 10; ++i) {
        int idx = base + i;
        if (idx < NN) offsets[idx] = thread_excl + loc[i];
    }
    if (t == 0) offsets[NN] = wsum[15];
}

// fused: edge fill (blocks 0..624) + x||h -> bf16 node-major xhb[n][4][256] (blocks 625..)
__global__ __launch_bounds__(256) void k_fillcvt(const int* __restrict__ ei,
                                                 const float* __restrict__ ew,
                                                 const float* __restrict__ dinv,
                                                 const int* __restrict__ offsets,
                                                 int* cursor, int2* __restrict__ ebuf,
                                                 const float* __restrict__ x,
                                                 const float* __restrict__ h,
                                                 unsigned short* __restrict__ xhb) {
    int bid = blockIdx.x;
    if (bid < 625) {
        int e = bid * 256 + threadIdx.x;  // exactly 160000
        int src = ei[e], dst = ei[NE + e];
        float norm = dinv[src] * ew[e] * dinv[dst];
        int pos = offsets[dst] + atomicAdd(&cursor[dst], 1);
        ebuf[pos] = make_int2(src, __float_as_int(norm));
    } else {
        int id = (bid - 625) * 256 + threadIdx.x;  // 0 .. 1,279,999
        int row = id >> 5;        // n*4 + b
        int k8 = (id & 31) << 3;  // 0..248
        int n = row >> 2, b = row & 3;
        const float* src = ((k8 >> 7) ? h : x) + ((size_t)b * NN + n) * 128 + (k8 & 127);
        float4 v0 = *(const float4*)src;
        float4 v1 = *(const float4*)(src + 4);
        bf16x8 o;
        o[0] = (short)f2bf(v0.x); o[1] = (short)f2bf(v0.y);
        o[2] = (short)f2bf(v0.z); o[3] = (short)f2bf(v0.w);
        o[4] = (short)f2bf(v1.x); o[5] = (short)f2bf(v1.y);
        o[6] = (short)f2bf(v1.z); o[7] = (short)f2bf(v1.w);
        *(bf16x8*)(xhb + (size_t)row * 256 + k8) = o;
    }
}

// ---------------- aggregation: 2 nodes per block, 128 threads per node ----------------
// thread tt (0..127): b = tt>>5, k8 = (tt&31)*8 ; per edge: 2KB contiguous gather per node
__global__ __launch_bounds__(256) void k_agg(const unsigned short* __restrict__ xhb,
                                             const float* __restrict__ dinv,
                                             const int* __restrict__ offsets,
                                             const int2* __restrict__ ebuf,
                                             unsigned short* __restrict__ aggb) {
    int t = threadIdx.x;
    int n = blockIdx.x * 2 + (t >> 7);
    int tt = t & 127;
    int b = tt >> 5;
    int k8 = (tt & 31) << 3;

    float acc[8] = {0.f, 0.f, 0.f, 0.f, 0.f, 0.f, 0.f, 0.f};
    int beg = offsets[n], end = offsets[n + 1];

#define EDGE_ACC(E)                                                          \
    {                                                                        \
        float w = __int_as_float((E).y);                                     \
        bf16x8 v = *(const bf16x8*)(xhb + (size_t)(E).x * 1024 + tt * 8);    \
        acc[0] = fmaf(w, bf2f((unsigned short)v[0]), acc[0]);                \
        acc[1] = fmaf(w, bf2f((unsigned short)v[1]), acc[1]);                \
        acc[2] = fmaf(w, bf2f((unsigned short)v[2]), acc[2]);                \
        acc[3] = fmaf(w, bf2f((unsigned short)v[3]), acc[3]);                \
        acc[4] = fmaf(w, bf2f((unsigned short)v[4]), acc[4]);                \
        acc[5] = fmaf(w, bf2f((unsigned short)v[5]), acc[5]);                \
        acc[6] = fmaf(w, bf2f((unsigned short)v[6]), acc[6]);                \
        acc[7] = fmaf(w, bf2f((unsigned short)v[7]), acc[7]);                \
    }

    int j = beg;
    for (; j + 4 <= end; j += 4) {
        int2 e0 = ebuf[j], e1 = ebuf[j + 1], e2 = ebuf[j + 2], e3 = ebuf[j + 3];
        EDGE_ACC(e0); EDGE_ACC(e1); EDGE_ACC(e2); EDGE_ACC(e3);
    }
    for (; j < end; ++j) {
        int2 e = ebuf[j];
        EDGE_ACC(e);
    }
    // self loop
    {
        float di = dinv[n];
        float w = di * di;
        bf16x8 v = *(const bf16x8*)(xhb + (size_t)n * 1024 + tt * 8);
        acc[0] = fmaf(w, bf2f((unsigned short)v[0]), acc[0]);
        acc[1] = fmaf(w, bf2f((unsigned short)v[1]), acc[1]);
        acc[2] = fmaf(w, bf2f((unsigned short)v[2]), acc[2]);
        acc[3] = fmaf(w, bf2f((unsigned short)v[3]), acc[3]);
        acc[4] = fmaf(w, bf2f((unsigned short)v[4]), acc[4]);
        acc[5] = fmaf(w, bf2f((unsigned short)v[5]), acc[5]);
        acc[6] = fmaf(w, bf2f((unsigned short)v[6]), acc[6]);
        acc[7] = fmaf(w, bf2f((unsigned short)v[7]), acc[7]);
    }
    bf16x8 o;
#pragma unroll
    for (int i = 0; i < 8; ++i) o[i] = (short)f2bf(acc[i]);
    *(bf16x8*)(aggb + ((size_t)b * NN + n) * 256 + k8) = o;
}

// ---------------- MFMA GEMM (40000x256 @ 256^T x 512) + fused LSTM gates ----------------
// block: 64 rows, 8 phases of 16 j-cols x 4 gates; A staged once (32KB), B per phase (32KB)
// LDS XOR-swizzle byte ^= (row&7)<<4, realized via pre-swizzled global source addresses.
__global__ __launch_bounds__(256) void k_gemm(const unsigned short* __restrict__ aggb,
                                              const unsigned short* __restrict__ Wt,
                                              const float* __restrict__ bcat,
                                              const float* __restrict__ c_in,
                                              float* __restrict__ out) {
    __shared__ __align__(16) unsigned short sA[64 * 256];
    __shared__ __align__(16) unsigned short sB[64 * 256];
    int t = threadIdx.x;
    int lane = t & 63, wid = t >> 6;
    int lr = lane & 15, lk = lane >> 4;  // lk in 0..3
    int rowbase = blockIdx.x * 64;

    // stage A: 64 rows x 512B, swizzled source -> linear LDS
#pragma unroll
    for (int i = 0; i < 8; ++i) {
        int idx = i * 256 + t;
        int row = idx >> 5;
        int cb = (idx & 31) << 4;
        const char* g = (const char*)aggb + (size_t)(rowbase + row) * 512 + (cb ^ ((row & 7) << 4));
        char* l = (char*)sA + (size_t)(i * 256 + wid * 64) * 16;
        GLOAD_LDS16(g, l);
    }

    f32x4 acc[4];
    for (int ph = 0; ph < 8; ++ph) {
        int jbase = ph * 16;
        __syncthreads();  // prev-phase sB reads done (and drains A-stage on ph=0)
        // stage B tile: rows rl = g*16 + jj -> Wt row g*128 + jbase + jj
#pragma unroll
        for (int i = 0; i < 8; ++i) {
            int idx = i * 256 + t;
            int rl = idx >> 5;
            int cb = (idx & 31) << 4;
            int grow = ((rl >> 4) << 7) + jbase + (rl & 15);
            const char* g = (const char*)Wt + (size_t)grow * 512 + (cb ^ ((rl & 7) << 4));
            char* l = (char*)sB + (size_t)(i * 256 + wid * 64) * 16;
            GLOAD_LDS16(g, l);
        }
        // prefetch c_in + biases for this phase (consumed after K loop)
        int j = jbase + lr;
        float bi = bcat[j], bfv = bcat[128 + j], bo = bcat[256 + j], bg = bcat[384 + j];
        float cv[4];
#pragma unroll
        for (int r = 0; r < 4; ++r)
            cv[r] = c_in[(size_t)(rowbase + wid * 16 + lk * 4 + r) * 128 + j];

        __syncthreads();  // B tile (and A on ph=0) resident

#pragma unroll
        for (int g = 0; g < 4; ++g) acc[g] = (f32x4)0.f;

        int arow = wid * 16 + lr;
        int asw = (arow & 7) << 4;
#pragma unroll
        for (int kb = 0; kb < 8; ++kb) {
            int koff = (kb << 6) + (lk << 4);
            bf16x8 a = *(const bf16x8*)((const char*)sA + arow * 512 + (koff ^ asw));
            bf16x8 b0 = *(const bf16x8*)((const char*)sB + (0 * 16 + lr) * 512 + (koff ^ ((lr & 7) << 4)));
            bf16x8 b1 = *(const bf16x8*)((const char*)sB + (1 * 16 + lr) * 512 + (koff ^ ((lr & 7) << 4)));
            bf16x8 b2 = *(const bf16x8*)((const char*)sB + (2 * 16 + lr) * 512 + (koff ^ ((lr & 7) << 4)));
            bf16x8 b3 = *(const bf16x8*)((const char*)sB + (3 * 16 + lr) * 512 + (koff ^ ((lr & 7) << 4)));
            acc[0] = __builtin_amdgcn_mfma_f32_16x16x32_bf16(a, b0, acc[0], 0, 0, 0);
            acc[1] = __builtin_amdgcn_mfma_f32_16x16x32_bf16(a, b1, acc[1], 0, 0, 0);
            acc[2] = __builtin_amdgcn_mfma_f32_16x16x32_bf16(a, b2, acc[2], 0, 0, 0);
            acc[3] = __builtin_amdgcn_mfma_f32_16x16x32_bf16(a, b3, acc[3], 0, 0, 0);
        }

        // fused LSTM epilogue for this phase's 16 j
#pragma unroll
        for (int r = 0; r < 4; ++r) {
            int row = rowbase + wid * 16 + lk * 4 + r;
            float vi = acc[0][r] + bi;
            float vf = acc[1][r] + bfv;
            float vo = acc[2][r] + bo;
            float vg = acc[3][r] + bg;
            float ig = 1.f / (1.f + __expf(-vi));
            float fg = 1.f / (1.f + __expf(-vf));
            float og = 1.f / (1.f + __expf(-vo));
            float gg = 1.f - 2.f / (__expf(2.f * vg) + 1.f);
            float cn = fg * cv[r] + ig * gg;
            float tc = 1.f - 2.f / (__expf(2.f * cn) + 1.f);
            size_t o = (size_t)row * 128 + j;
            out[o] = og * tc;
            out[(size_t)NB * NN * 128 + o] = cn;
        }
    }
}

// ---------------- launch ----------------

extern "C" void kernel_launch(void* const* d_in, const int* in_sizes, int n_in,
                              void* d_out, int out_size, void* d_ws, size_t ws_size,
                              hipStream_t stream) {
    const float* x = (const float*)d_in[0];
    const float* h = (const float*)d_in[1];
    const float* c = (const float*)d_in[2];
    const int* ei = (const int*)d_in[3];
    const float* ew = (const float*)d_in[4];
    const float* Wi = (const float*)d_in[5];
    const float* bi = (const float*)d_in[6];
    const float* Wf = (const float*)d_in[7];
    const float* bf = (const float*)d_in[8];
    const float* Wo = (const float*)d_in[9];
    const float* bo = (const float*)d_in[10];
    const float* Wg = (const float*)d_in[11];
    const float* bg = (const float*)d_in[12];
    float* out = (float*)d_out;

    char* ws = (char*)d_ws;
    size_t off = 0;
    auto alloc = [&](size_t bytes) {
        void* p = ws + off;
        off = (off + bytes + 255) & ~(size_t)255;
        return p;
    };
    float* deg = (float*)alloc((size_t)NN * 4);  // becomes dinv
    int* cnt = (int*)alloc((size_t)NN * 4);
    int* offsets = (int*)alloc((size_t)(NN + 1) * 4);
    int* cursor = (int*)alloc((size_t)NN * 4);
    float* bcat = (float*)alloc((size_t)DOUT * 4);
    unsigned short* Wt = (unsigned short*)alloc((size_t)DOUT * DIN * 2);
    int2* ebuf = (int2*)alloc((size_t)NE * 8);
    unsigned short* xhb = (unsigned short*)alloc((size_t)NN * 4 * DIN * 2);   // node-major [n][b][k]
    unsigned short* aggb = (unsigned short*)alloc((size_t)NB * NN * DIN * 2); // batch-major [b][n][k]

    hipLaunchKernelGGL(k_pack, dim3(512), dim3(256), 0, stream,
                       Wi, Wf, Wo, Wg, bi, bf, bo, bg, deg, cnt, cursor, Wt, bcat);
    hipLaunchKernelGGL(k_degcnt, dim3(625), dim3(256), 0, stream, ei, ew, deg, cnt);
    hipLaunchKernelGGL(k_scanrs, dim3(1), dim3(1024), 0, stream, deg, cnt, offsets);
    hipLaunchKernelGGL(k_fillcvt, dim3(625 + 5000), dim3(256), 0, stream,
                       ei, ew, deg, offsets, cursor, ebuf, x, h, xhb);
    hipLaunchKernelGGL(k_agg, dim3(5000), dim3(256), 0, stream, xhb, deg, offsets, ebuf, aggb);
    hipLaunchKernelGGL(k_gemm, dim3(625), dim3(256), 0, stream, aggb, Wt, bcat, c, out);
}